// Round 14
// baseline (1198.313 us; speedup 1.0000x reference)
//
#include <hip/hip_runtime.h>
#include <hip/hip_fp16.h>
#include <math.h>

// Problem constants: B=8, Tt=16, C=1, H=W=512, 4 in-channels, 10 T-planes.
#define Bd 8
#define Td 16
#define Hd 512
#define Wd 512
#define HWc (Hd * Wd)          // 262144
#define NPIX (Bd * HWc)        // 2,097,152

// ---------------- conv tiling (round-7 proven): 128x8 tile, 2 px/thread ------
#define CTW 128
#define CTH 8
#define CRW 130
#define CRH 10
#define CPITCH 132
#define CTHR 512

// ---------------- fused lane-column kernel -----------------------------------
#define KCR 64                 // core rows
#define KCC 52                 // core cols
#define KH  6                  // halo
#define KTR 76                 // region rows
#define KTC 64                 // region cols == lanes of one wave
#define KG  7                  // waves (row groups) per block
#define KR  11                 // owned rows per thread
#define KTHR (KG * 64)         // 448 threads

// Whole-wave lane shifts: left neighbor = lane-1 (wave_shr:1), right = lane+1
// (wave_shl:1). Invalid edge lanes produce 0 / own value -- both feed only
// ring-column outputs which are never written. VALU-pipe (2 cyc) vs LDS-pipe.
__device__ __forceinline__ float lane_left(float v) {
#if __has_builtin(__builtin_amdgcn_mov_dpp)
    return __int_as_float(__builtin_amdgcn_mov_dpp(__float_as_int(v),
                                                   0x138, 0xf, 0xf, true));
#else
    return __shfl_up(v, 1);
#endif
}
__device__ __forceinline__ float lane_right(float v) {
#if __has_builtin(__builtin_amdgcn_mov_dpp)
    return __int_as_float(__builtin_amdgcn_mov_dpp(__float_as_int(v),
                                                   0x130, 0xf, 0xf, true));
#else
    return __shfl_down(v, 1);
#endif
}

// ---------------------------------------------------------------------------
// Kernel 1 (round-7 exact): tiled conv T = conv2d(x[:,-4:,0],W)+b, fused with
// xt0 = stencil(x[:,15,0], T_fp32) -> out[:,0].
// T stored as half2 pairs: plane q holds (T[2q], T[2q+1]); layout (B,5,H,W).
// ---------------------------------------------------------------------------
__global__ __launch_bounds__(CTHR)
void conv_step0_kernel(const float* __restrict__ x,
                       const float* __restrict__ Wu,
                       const float* __restrict__ bu,
                       __half2* __restrict__ T,
                       float* __restrict__ out) {
    __shared__ __align__(16) float sX[4][CRH][CPITCH];

    int bx  = blockIdx.x;           // 2048 = 8 b * 64 row-bands * 4 col-bands
    int b   = bx >> 8;
    int rem = bx & 255;
    int by  = rem >> 2;
    int bc  = rem & 3;
    int i0  = by * CTH;
    int j0  = bc * CTW;

    const float* xb = x + ((size_t)b * Td + 12) * HWc;
    int tid = threadIdx.x;

    for (int idx = tid; idx < 4 * CRH * CRW; idx += CTHR) {
        int ch = idx / (CRH * CRW);
        int r2 = idx - ch * (CRH * CRW);
        int r  = r2 / CRW;
        int c  = r2 - r * CRW;
        int gi = i0 + r - 1, gj = j0 + c - 1;
        float v = 0.0f;
        if ((unsigned)gi < (unsigned)Hd && (unsigned)gj < (unsigned)Wd)
            v = xb[(size_t)ch * HWc + gi * Wd + gj];
        sX[ch][r][c] = v;
    }
    __syncthreads();

    int tx = tid & 63;              // pixel pair: cols 2tx, 2tx+1
    int ty = tid >> 6;              // tile row 0..7

    float t0[10], t1[10];
    #pragma unroll
    for (int o = 0; o < 10; ++o) { float bv = bu[o]; t0[o] = bv; t1[o] = bv; }

    #pragma unroll
    for (int ch = 0; ch < 4; ++ch)
        #pragma unroll
        for (int kh = 0; kh < 3; ++kh) {
            const float* rp = &sX[ch][ty + kh][2 * tx];
            float2 a  = *(const float2*)rp;
            float2 b2 = *(const float2*)(rp + 2);
            float w0 = a.x, w1 = a.y, w2 = b2.x, w3 = b2.y;
            #pragma unroll
            for (int o = 0; o < 10; ++o) {
                float wt0 = Wu[((o * 4 + ch) * 3 + kh) * 3 + 0];
                float wt1 = Wu[((o * 4 + ch) * 3 + kh) * 3 + 1];
                float wt2 = Wu[((o * 4 + ch) * 3 + kh) * 3 + 2];
                t0[o] += w0 * wt0 + w1 * wt1 + w2 * wt2;
                t1[o] += w1 * wt0 + w2 * wt1 + w3 * wt2;
            }
        }

    int gi = i0 + ty;
    int gjv = j0 + 2 * tx;
    size_t pix = (size_t)gi * Wd + gjv;
    __half2* Tb = T + (size_t)b * 5 * HWc;
    #pragma unroll
    for (int q = 0; q < 5; ++q) {
        __half2 h0 = __floats2half2_rn(t0[2 * q], t0[2 * q + 1]);
        __half2 h1 = __floats2half2_rn(t1[2 * q], t1[2 * q + 1]);
        uint2 pk;
        pk.x = *(unsigned*)&h0;
        pk.y = *(unsigned*)&h1;
        *(uint2*)(Tb + (size_t)q * HWc + pix) = pk;
    }

    float o0 = t0[9], o1 = t1[9];
    #pragma unroll
    for (int di = 0; di < 3; ++di) {
        const float* rp = &sX[3][ty + di][2 * tx];
        float2 a  = *(const float2*)rp;
        float2 b2 = *(const float2*)(rp + 2);
        float w0 = a.x, w1 = a.y, w2 = b2.x, w3 = b2.y;
        #pragma unroll
        for (int dj = 0; dj < 3; ++dj) {
            float xa = (dj == 0) ? w0 : ((dj == 1) ? w1 : w2);
            float xc = (dj == 0) ? w1 : ((dj == 1) ? w2 : w3);
            o0 += xa * t0[dj * 3 + di];
            o1 += xc * t1[dj * 3 + di];
        }
    }
    float2 ov; ov.x = o0; ov.y = o1;
    *(float2*)(out + (size_t)b * Td * HWc + pix) = ov;
}

// ---------------------------------------------------------------------------
// Kernel 2: one scan-body iteration = 6 fused stencil steps, lane-column
// layout. Wave g owns region rows rs..rs+10 (rs=1+11g), lane = region col.
// Column state in registers (xw[13]: rows rs-1..rs+11); horizontal neighbors
// via DPP lane shifts; vertical in-register; only the 2 group-boundary rows
// go through LDS each step (double-buffered, 1 barrier/step).
// Ring rows (0,75) / ring cols (0,63) are never updated -> keep staged
// x_{t-1} values; validity after 6 steps = rows[6,69] x cols[6,57] = core.
// Out-of-image pixels forced 0 every step (zero-pad semantics).
// 640 blocks = 8 b * 8 row-tiles * 10 col-tiles; 448 thr; ~2 blocks/CU.
// ---------------------------------------------------------------------------
__global__ __launch_bounds__(KTHR, 4)
void fused6_lane_kernel(const float* __restrict__ xin,   // out slot t-1 base
                        const __half2* __restrict__ T,
                        float* __restrict__ xout) {      // out slot t base
    __shared__ float bndF[2][KG][64];   // first-row values per group
    __shared__ float bndL[2][KG][64];   // last-row values per group

    int tile = blockIdx.x;              // 640
    int b   = tile / 80;
    int rem = tile - b * 80;
    int tr  = rem / 10;
    int tc  = rem - tr * 10;
    int ri  = tr * KCR - KH;
    int rj  = tc * KCC - KH;

    int tid  = threadIdx.x;
    int g    = tid >> 6;                // wave-uniform group 0..6
    int lane = tid & 63;

    int  gj     = rj + lane;
    bool colin  = (unsigned)gj < (unsigned)Wd;      // in-image col
    bool lanein = (lane >= 1) && (lane <= KTC - 2); // interior region col
    int  gjc    = min(max(gj, 0), Wd - 1);          // clamped address col

    int rs = 1 + g * KR;                // first owned region row

    const float* xb = xin + (size_t)b * Td * HWc;
    const __half2* Tb = T + (size_t)b * 5 * HWc;

    // Initial column state: rows rs-1 .. rs+11 (13 values), zero outside image.
    float xw[KR + 2];
    #pragma unroll
    for (int k = 0; k < KR + 2; ++k) {
        int row = rs - 1 + k;
        int gi  = ri + row;
        bool in = ((unsigned)gi < (unsigned)Hd) && colin && (row <= KTR - 1);
        int gic = min(max(gi, 0), Hd - 1);
        float v = xb[gic * Wd + gjc];
        xw[k] = in ? v : 0.0f;
    }

    // T coefficients for the 11 owned rows (clamped addresses; garbage values
    // only ever feed masked-off outputs).
    __half2 treg[KR][5];
    #pragma unroll
    for (int j = 0; j < KR; ++j) {
        int gi  = ri + rs + j;
        int gic = min(max(gi, 0), Hd - 1);
        const __half2* tp = Tb + gic * Wd + gjc;
        #pragma unroll
        for (int q = 0; q < 5; ++q)
            treg[j][q] = tp[(size_t)q * HWc];
    }

    int p = 0;
    #pragma unroll
    for (int s = 1; s <= 6; ++s) {
        // Streaming 3-row window over the column triple (L, C, R).
        float pC = xw[0], pL = lane_left(pC), pR = lane_right(pC);
        float cC = xw[1], cL = lane_left(cC), cR = lane_right(cC);
        #pragma unroll
        for (int j = 1; j <= KR; ++j) {
            float nC = xw[j + 1];
            float nL = lane_left(nC);
            float nR = lane_right(nC);
            __half2 h0 = treg[j - 1][0], h1 = treg[j - 1][1],
                    h2 = treg[j - 1][2], h3 = treg[j - 1][3],
                    h4 = treg[j - 1][4];
            // k = dj*3+di multiplies x[r+di-1][c+dj-1]
            float a = __half2float(__high2half(h4));          // T9
            a += pL * __half2float(__low2half(h0));           // k0
            a += cL * __half2float(__high2half(h0));          // k1
            a += nL * __half2float(__low2half(h1));           // k2
            a += pC * __half2float(__high2half(h1));          // k3
            a += cC * __half2float(__low2half(h2));           // k4
            a += nC * __half2float(__high2half(h2));          // k5
            a += pR * __half2float(__low2half(h3));           // k6
            a += cR * __half2float(__high2half(h3));          // k7
            a += nR * __half2float(__low2half(h4));           // k8
            if ((s & 1) == 0) a = 1.0f / (1.0f + __expf(-a));

            int row = rs + j - 1;
            int gi  = ri + row;
            bool okpix = ((unsigned)gi < (unsigned)Hd) && colin;
            bool upd   = (row <= KTR - 2) && lanein;   // row >= 1 guaranteed
            float val  = okpix ? a : 0.0f;
            xw[j] = upd ? val : xw[j];

            pL = cL; pC = cC; pR = cR;
            cL = nL; cC = nC; cR = nR;
        }
        // Exchange group-boundary rows (double-buffered; one barrier/step).
        bndF[p][g][lane] = xw[1];
        bndL[p][g][lane] = xw[KR];
        __syncthreads();
        if (g > 0)      xw[0]      = bndL[p][g - 1][lane];
        if (g < KG - 1) xw[KR + 1] = bndF[p][g + 1][lane];
        p ^= 1;
    }

    // Store the 64x52 core (region rows 6..69, cols 6..57), masked to image.
    float* ob = xout + (size_t)b * Td * HWc;
    bool storec = (lane >= KH) && (lane <= KTC - 1 - KH) && colin;
    #pragma unroll
    for (int j = 1; j <= KR; ++j) {
        int row = rs + j - 1;
        if (row >= KH && row <= KTR - 1 - KH) {     // wave-uniform branch
            int gi = ri + row;                      // always in [0,511]
            if (storec) ob[gi * Wd + gj] = xw[j];
        }
    }
}

// ---------------------------------------------------------------------------
// Workspace: T only (B*5*H*W half2 = 40 MB).
// ---------------------------------------------------------------------------
extern "C" void kernel_launch(void* const* d_in, const int* in_sizes, int n_in,
                              void* d_out, int out_size, void* d_ws, size_t ws_size,
                              hipStream_t stream) {
    const float* x  = (const float*)d_in[0];
    const float* Wu = (const float*)d_in[1];
    const float* bu = (const float*)d_in[2];
    float* out = (float*)d_out;
    __half2* T = (__half2*)d_ws;

    conv_step0_kernel<<<2048, CTHR, 0, stream>>>(x, Wu, bu, T, out);

    for (int t = 1; t < Td; ++t)
        fused6_lane_kernel<<<640, KTHR, 0, stream>>>(out + (size_t)(t - 1) * HWc, T,
                                                     out + (size_t)t * HWc);
}

// Round 15
// 546.780 us; speedup vs baseline: 2.1916x; 2.1916x over previous
//
#include <hip/hip_runtime.h>
#include <hip/hip_fp16.h>
#include <math.h>

// Problem constants: B=8, Tt=16, C=1, H=W=512, 4 in-channels, 10 T-planes.
#define Bd 8
#define Td 16
#define Hd 512
#define Wd 512
#define HWc (Hd * Wd)          // 262144
#define NPIX (Bd * HWc)        // 2,097,152

// ---------------- conv tiling: 128x16 tile, 4 px/thread (2x2), 512 threads ---
#define VTW 128
#define VTH 16
#define VRW 130
#define VRH 18
#define VP  132
#define VTHR 512

// ---------------- fused-step tiling: 128x64 core, halo 6 ---------------------
#define WCR 128                // core rows
#define WCC 64                 // core cols
#define WH  6                  // halo
#define WTR 140                // region rows
#define WTC 76                 // region cols
#define WLP 77                 // LDS row pitch
#define WTHR 1024
#define WRPG 11                // owned rows per thread
#define WNG 13                 // row groups (13*11 = 143 >= 138 interior rows)

// ---------------------------------------------------------------------------
// Kernel 1: tiled conv  T = conv2d(x[:, -4:, 0], W_unet, SAME) + b_unet,
// fused with xt0 = stencil(x[:,15,0], T_fp32) -> out[:, 0].  (r12 verbatim)
// T stored as half2 pairs: plane q holds (T[2q], T[2q+1]); layout (B,5,H,W).
// ---------------------------------------------------------------------------
__global__ __launch_bounds__(VTHR, 4)
void conv_step0_kernel(const float* __restrict__ x,
                       const float* __restrict__ Wu,
                       const float* __restrict__ bu,
                       __half2* __restrict__ T,
                       float* __restrict__ out) {
    __shared__ __align__(16) float sX[4][VRH][VP];   // 38 KB

    int bx  = blockIdx.x;           // 1024 = 8 b * 32 row-bands * 4 col-bands
    int b   = bx >> 7;
    int rem = bx & 127;
    int by  = rem >> 2;
    int bc  = rem & 3;
    int i0  = by * VTH;
    int j0  = bc * VTW;

    const float* xb = x + ((size_t)b * Td + 12) * HWc;
    int tid = threadIdx.x;

    for (int idx = tid; idx < 4 * VRH * VRW; idx += VTHR) {
        int ch = idx / (VRH * VRW);
        int r2 = idx - ch * (VRH * VRW);
        int r  = r2 / VRW;
        int c  = r2 - r * VRW;
        int gi = i0 + r - 1, gj = j0 + c - 1;
        float v = 0.0f;
        if ((unsigned)gi < (unsigned)Hd && (unsigned)gj < (unsigned)Wd)
            v = xb[(size_t)ch * HWc + gi * Wd + gj];
        sX[ch][r][c] = v;
    }
    __syncthreads();

    int tx = tid & 63;              // col pair: cols 2tx, 2tx+1
    int ty = tid >> 6;              // row pair: rows 2ty, 2ty+1

    float t00[10], t01[10], t10[10], t11[10];
    #pragma unroll
    for (int o = 0; o < 10; ++o) {
        float bv = bu[o];
        t00[o] = bv; t01[o] = bv; t10[o] = bv; t11[o] = bv;
    }

    float w[4][4];
    #pragma unroll
    for (int ch = 0; ch < 4; ++ch) {
        #pragma unroll
        for (int rr = 0; rr < 4; ++rr) {
            const float* rp = &sX[ch][2 * ty + rr][2 * tx];
            float2 a  = *(const float2*)rp;
            float2 b2 = *(const float2*)(rp + 2);
            w[rr][0] = a.x; w[rr][1] = a.y; w[rr][2] = b2.x; w[rr][3] = b2.y;
        }
        #pragma unroll
        for (int kh = 0; kh < 3; ++kh) {
            #pragma unroll
            for (int o = 0; o < 10; ++o) {
                float wt0 = Wu[((o * 4 + ch) * 3 + kh) * 3 + 0];
                float wt1 = Wu[((o * 4 + ch) * 3 + kh) * 3 + 1];
                float wt2 = Wu[((o * 4 + ch) * 3 + kh) * 3 + 2];
                t00[o] += w[kh][0] * wt0 + w[kh][1] * wt1 + w[kh][2] * wt2;
                t01[o] += w[kh][1] * wt0 + w[kh][2] * wt1 + w[kh][3] * wt2;
                t10[o] += w[kh + 1][0] * wt0 + w[kh + 1][1] * wt1 + w[kh + 1][2] * wt2;
                t11[o] += w[kh + 1][1] * wt0 + w[kh + 1][2] * wt1 + w[kh + 1][3] * wt2;
            }
        }
    }
    // w[][] now holds channel 3 (= x slice 15).

    int gi0 = i0 + 2 * ty;
    int gj0 = j0 + 2 * tx;
    size_t pix0 = (size_t)gi0 * Wd + gj0;
    size_t pix1 = pix0 + Wd;
    __half2* Tb = T + (size_t)b * 5 * HWc;
    #pragma unroll
    for (int q = 0; q < 5; ++q) {
        __half2 a0 = __floats2half2_rn(t00[2 * q], t00[2 * q + 1]);
        __half2 a1 = __floats2half2_rn(t01[2 * q], t01[2 * q + 1]);
        __half2 b0 = __floats2half2_rn(t10[2 * q], t10[2 * q + 1]);
        __half2 b1 = __floats2half2_rn(t11[2 * q], t11[2 * q + 1]);
        uint2 p0, p1;
        p0.x = *(unsigned*)&a0; p0.y = *(unsigned*)&a1;
        p1.x = *(unsigned*)&b0; p1.y = *(unsigned*)&b1;
        *(uint2*)(Tb + (size_t)q * HWc + pix0) = p0;
        *(uint2*)(Tb + (size_t)q * HWc + pix1) = p1;
    }

    // step0 on channel 3: k = dj*3+di multiplies x15[i+di-1, j+dj-1].
    float o00 = t00[9], o01 = t01[9], o10 = t10[9], o11 = t11[9];
    #pragma unroll
    for (int dj = 0; dj < 3; ++dj)
        #pragma unroll
        for (int di = 0; di < 3; ++di) {
            int k = dj * 3 + di;
            o00 += w[di][dj]         * t00[k];
            o01 += w[di][dj + 1]     * t01[k];
            o10 += w[di + 1][dj]     * t10[k];
            o11 += w[di + 1][dj + 1] * t11[k];
        }
    float* ob = out + (size_t)b * Td * HWc;
    float2 v0; v0.x = o00; v0.y = o01;
    float2 v1; v1.x = o10; v1.y = o11;
    *(float2*)(ob + pix0) = v0;
    *(float2*)(ob + pix1) = v1;
}

// ---------------------------------------------------------------------------
// Kernel 2 (r12 verbatim, ONE change: launch_bounds(1024,2) instead of
// (1024,4) — on this toolchain second-arg=4 squeezes to a 64-VGPR cap and
// spills the 55-reg treg to scratch; 1024-thr blocks hard-cap at 128 anyway).
// One scan-body iteration = 6 fused stencil steps, 128x64 core (region
// 140x76), 256 blocks = 1 block/CU, one round. Thread owns column c = t%76,
// rows rs..rs+10; 55 half2 T coefs in VGPRs; x ping-pongs in LDS (2x43 KB).
// Sigmoid at even sub-steps. Region ring never written; contamination <=1
// px/step; halo 6 protects the core.
// ---------------------------------------------------------------------------
__global__ __launch_bounds__(WTHR, 2)
void fused6_wide_kernel(const float* __restrict__ xin,   // out slot t-1 base
                        const __half2* __restrict__ T,
                        float* __restrict__ xout) {      // out slot t base
    __shared__ float sA[WTR * WLP];
    __shared__ float sB[WTR * WLP];

    int tile = blockIdx.x;          // 256 = 8 b * 4 tr * 8 tc
    int b  = tile >> 5;
    int tr = (tile >> 3) & 3;
    int tc = tile & 7;
    int ri = tr * WCR - WH;
    int rj = tc * WCC - WH;

    const float* xb = xin + (size_t)b * Td * HWc;
    const __half2* Tb = T + (size_t)b * 5 * HWc;
    int tid = threadIdx.x;

    // Stage sA (zeros outside image).
    for (int idx = tid; idx < WTR * WTC; idx += WTHR) {
        int r = idx / WTC, c = idx - r * WTC;
        int gi = ri + r, gj = rj + c;
        float v = 0.0f;
        if ((unsigned)gi < (unsigned)Hd && (unsigned)gj < (unsigned)Wd)
            v = xb[gi * Wd + gj];
        sA[r * WLP + c] = v;
    }
    // Zero only sB's ring (never written by the step loop; interior is fully
    // rewritten each step before being read).
    for (int idx = tid; idx < 2 * WTC; idx += WTHR) {
        int r = (idx < WTC) ? 0 : (WTR - 1);
        int c = (idx < WTC) ? idx : idx - WTC;
        sB[r * WLP + c] = 0.0f;
    }
    for (int idx = tid; idx < 2 * WTR; idx += WTHR) {
        int r = (idx < WTR) ? idx : idx - WTR;
        int c = (idx < WTR) ? 0 : (WTC - 1);
        sB[r * WLP + c] = 0.0f;
    }

    int g  = tid / WTC;             // row group 0..12 valid
    int c  = tid - g * WTC;         // column 0..75
    int rs = 1 + g * WRPG;          // first owned row
    bool colint = (c >= 1) && (c <= WTC - 2);
    bool active = (g < WNG) && colint;
    int  gj     = rj + c;
    bool colin  = (unsigned)gj < (unsigned)Wd;

    // T coefficients: 5 half2 per owned row.
    __half2 treg[WRPG][5];
    #pragma unroll
    for (int jj = 0; jj < WRPG; ++jj) {
        int r  = rs + jj;
        int gi = ri + r;
        bool ok = active && (r <= WTR - 2) && ((unsigned)gi < (unsigned)Hd) && colin;
        #pragma unroll
        for (int q = 0; q < 5; ++q)
            treg[jj][q] = ok ? Tb[(size_t)q * HWc + gi * Wd + gj]
                             : __floats2half2_rn(0.0f, 0.0f);
    }
    __syncthreads();

    float* cur = sA;
    float* nxt = sB;

    #pragma unroll
    for (int s = 1; s <= 6; ++s) {
        if (active) {
            float w00 = cur[(rs - 1) * WLP + c - 1];
            float w01 = cur[(rs - 1) * WLP + c];
            float w02 = cur[(rs - 1) * WLP + c + 1];
            float w10 = cur[rs * WLP + c - 1];
            float w11 = cur[rs * WLP + c];
            float w12 = cur[rs * WLP + c + 1];
            #pragma unroll
            for (int jj = 0; jj < WRPG; ++jj) {
                int r  = rs + jj;
                int r2 = (r + 1 <= WTR - 1) ? (r + 1) : (WTR - 1);  // clamp tail
                float w20 = cur[r2 * WLP + c - 1];
                float w21 = cur[r2 * WLP + c];
                float w22 = cur[r2 * WLP + c + 1];

                float2 p0 = __half22float2(treg[jj][0]);  // T0,T1
                float2 p1 = __half22float2(treg[jj][1]);  // T2,T3
                float2 p2 = __half22float2(treg[jj][2]);  // T4,T5
                float2 p3 = __half22float2(treg[jj][3]);  // T6,T7
                float2 p4 = __half22float2(treg[jj][4]);  // T8,T9

                // k = dj*3+di multiplies x[r+di-1][c+dj-1]
                float a = p4.y
                        + w00 * p0.x + w10 * p0.y + w20 * p1.x
                        + w01 * p1.y + w11 * p2.x + w21 * p2.y
                        + w02 * p3.x + w12 * p3.y + w22 * p4.x;
                if ((s & 1) == 0) a = 1.0f / (1.0f + __expf(-a));

                int gi = ri + r;
                bool rowok = (r <= WTR - 2);
                bool inimg = ((unsigned)gi < (unsigned)Hd) && colin;
                if (rowok) nxt[r * WLP + c] = inimg ? a : 0.0f;

                w00 = w10; w01 = w11; w02 = w12;
                w10 = w20; w11 = w21; w12 = w22;
            }
        }
        __syncthreads();
        float* tmp = cur; cur = nxt; nxt = tmp;
    }

    // After 6 swaps the result is back in sA (== cur). Write 128x64 core.
    float* ob = xout + (size_t)b * Td * HWc;
    for (int idx = tid; idx < WCR * WCC; idx += WTHR) {
        int rr = idx >> 6, cc = idx & 63;
        ob[(ri + WH + rr) * Wd + (rj + WH + cc)] = cur[(WH + rr) * WLP + (WH + cc)];
    }
}

// ---------------------------------------------------------------------------
// Workspace: T only (B*5*H*W half2 = 40 MB).
// ---------------------------------------------------------------------------
extern "C" void kernel_launch(void* const* d_in, const int* in_sizes, int n_in,
                              void* d_out, int out_size, void* d_ws, size_t ws_size,
                              hipStream_t stream) {
    const float* x  = (const float*)d_in[0];
    const float* Wu = (const float*)d_in[1];
    const float* bu = (const float*)d_in[2];
    float* out = (float*)d_out;
    __half2* T = (__half2*)d_ws;

    conv_step0_kernel<<<1024, VTHR, 0, stream>>>(x, Wu, bu, T, out);

    for (int t = 1; t < Td; ++t)
        fused6_wide_kernel<<<256, WTHR, 0, stream>>>(out + (size_t)(t - 1) * HWc, T,
                                                     out + (size_t)t * HWc);
}

// Round 16
// 532.898 us; speedup vs baseline: 2.2487x; 1.0261x over previous
//
#include <hip/hip_runtime.h>
#include <hip/hip_fp16.h>
#include <math.h>

// Problem constants: B=8, Tt=16, C=1, H=W=512, 4 in-channels, 10 T-planes.
#define Bd 8
#define Td 16
#define Hd 512
#define Wd 512
#define HWc (Hd * Wd)          // 262144
#define NPIX (Bd * HWc)        // 2,097,152

// ---------------- conv tiling: 128x16 tile, 4 px/thread (2x2), 512 threads ---
#define VTW 128
#define VTH 16
#define VRW 130
#define VRH 18
#define VP  132
#define VTHR 512

// ---------------- wide fused kernel (fallback): 128x64 core, halo 6 ----------
#define WCR 128
#define WCC 64
#define WH  6
#define WTR 140
#define WTC 76
#define WLP 77
#define WTHR 1024
#define WRPG 11
#define WNG 13

// ---------------- lane-column fused kernel -----------------------------------
#define KCR 64                 // core rows
#define KCC 52                 // core cols
#define KH  6                  // halo
#define KTR 76                 // region rows
#define KTC 64                 // region cols == lanes of one wave
#define KG  7                  // waves (row groups) per block
#define KR  11                 // owned rows per thread
#define KTHR (KG * 64)         // 448 threads

// v_fma_mix_f32: acc(f32) += w(f32) * h.lo/h.hi(f16) in ONE instruction —
// replaces cvt+fma. op_sel_hi[1]=1 marks src1 as fp16; op_sel[1] picks half.
#define FMAMIX_LO(acc, wv, hv) \
    asm("v_fma_mix_f32 %0, %1, %2, %0 op_sel:[0,0,0] op_sel_hi:[0,1,0]" \
        : "+v"(acc) : "v"(wv), "v"(hv))
#define FMAMIX_HI(acc, wv, hv) \
    asm("v_fma_mix_f32 %0, %1, %2, %0 op_sel:[0,1,0] op_sel_hi:[0,1,0]" \
        : "+v"(acc) : "v"(wv), "v"(hv))

__device__ __forceinline__ float hi_half_f32(unsigned h) {
    __half2 hh = *(__half2*)&h;
    return __half2float(__high2half(hh));
}

// Whole-wave lane shifts (verified r14): left = lane-1, right = lane+1.
// Invalid edge lanes feed only ring-column outputs which are never written.
__device__ __forceinline__ float lane_left(float v) {
#if __has_builtin(__builtin_amdgcn_mov_dpp)
    return __int_as_float(__builtin_amdgcn_mov_dpp(__float_as_int(v),
                                                   0x138, 0xf, 0xf, true));
#else
    return __shfl_up(v, 1);
#endif
}
__device__ __forceinline__ float lane_right(float v) {
#if __has_builtin(__builtin_amdgcn_mov_dpp)
    return __int_as_float(__builtin_amdgcn_mov_dpp(__float_as_int(v),
                                                   0x130, 0xf, 0xf, true));
#else
    return __shfl_down(v, 1);
#endif
}

// ---------------------------------------------------------------------------
// Kernel 1 (r12 verbatim): tiled conv T = conv2d(x[:,-4:,0],W)+b fused with
// xt0 = stencil(x[:,15,0], T_fp32) -> out[:,0].
// T stored as half2 pairs: plane q holds (T[2q], T[2q+1]); layout (B,5,H,W).
// ---------------------------------------------------------------------------
__global__ __launch_bounds__(VTHR, 4)
void conv_step0_kernel(const float* __restrict__ x,
                       const float* __restrict__ Wu,
                       const float* __restrict__ bu,
                       __half2* __restrict__ T,
                       float* __restrict__ out) {
    __shared__ __align__(16) float sX[4][VRH][VP];   // 38 KB

    int bx  = blockIdx.x;           // 1024 = 8 b * 32 row-bands * 4 col-bands
    int b   = bx >> 7;
    int rem = bx & 127;
    int by  = rem >> 2;
    int bc  = rem & 3;
    int i0  = by * VTH;
    int j0  = bc * VTW;

    const float* xb = x + ((size_t)b * Td + 12) * HWc;
    int tid = threadIdx.x;

    for (int idx = tid; idx < 4 * VRH * VRW; idx += VTHR) {
        int ch = idx / (VRH * VRW);
        int r2 = idx - ch * (VRH * VRW);
        int r  = r2 / VRW;
        int c  = r2 - r * VRW;
        int gi = i0 + r - 1, gj = j0 + c - 1;
        float v = 0.0f;
        if ((unsigned)gi < (unsigned)Hd && (unsigned)gj < (unsigned)Wd)
            v = xb[(size_t)ch * HWc + gi * Wd + gj];
        sX[ch][r][c] = v;
    }
    __syncthreads();

    int tx = tid & 63;              // col pair: cols 2tx, 2tx+1
    int ty = tid >> 6;              // row pair: rows 2ty, 2ty+1

    float t00[10], t01[10], t10[10], t11[10];
    #pragma unroll
    for (int o = 0; o < 10; ++o) {
        float bv = bu[o];
        t00[o] = bv; t01[o] = bv; t10[o] = bv; t11[o] = bv;
    }

    float w[4][4];
    #pragma unroll
    for (int ch = 0; ch < 4; ++ch) {
        #pragma unroll
        for (int rr = 0; rr < 4; ++rr) {
            const float* rp = &sX[ch][2 * ty + rr][2 * tx];
            float2 a  = *(const float2*)rp;
            float2 b2 = *(const float2*)(rp + 2);
            w[rr][0] = a.x; w[rr][1] = a.y; w[rr][2] = b2.x; w[rr][3] = b2.y;
        }
        #pragma unroll
        for (int kh = 0; kh < 3; ++kh) {
            #pragma unroll
            for (int o = 0; o < 10; ++o) {
                float wt0 = Wu[((o * 4 + ch) * 3 + kh) * 3 + 0];
                float wt1 = Wu[((o * 4 + ch) * 3 + kh) * 3 + 1];
                float wt2 = Wu[((o * 4 + ch) * 3 + kh) * 3 + 2];
                t00[o] += w[kh][0] * wt0 + w[kh][1] * wt1 + w[kh][2] * wt2;
                t01[o] += w[kh][1] * wt0 + w[kh][2] * wt1 + w[kh][3] * wt2;
                t10[o] += w[kh + 1][0] * wt0 + w[kh + 1][1] * wt1 + w[kh + 1][2] * wt2;
                t11[o] += w[kh + 1][1] * wt0 + w[kh + 1][2] * wt1 + w[kh + 1][3] * wt2;
            }
        }
    }
    // w[][] now holds channel 3 (= x slice 15).

    int gi0 = i0 + 2 * ty;
    int gj0 = j0 + 2 * tx;
    size_t pix0 = (size_t)gi0 * Wd + gj0;
    size_t pix1 = pix0 + Wd;
    __half2* Tb = T + (size_t)b * 5 * HWc;
    #pragma unroll
    for (int q = 0; q < 5; ++q) {
        __half2 a0 = __floats2half2_rn(t00[2 * q], t00[2 * q + 1]);
        __half2 a1 = __floats2half2_rn(t01[2 * q], t01[2 * q + 1]);
        __half2 b0 = __floats2half2_rn(t10[2 * q], t10[2 * q + 1]);
        __half2 b1 = __floats2half2_rn(t11[2 * q], t11[2 * q + 1]);
        uint2 p0, p1;
        p0.x = *(unsigned*)&a0; p0.y = *(unsigned*)&a1;
        p1.x = *(unsigned*)&b0; p1.y = *(unsigned*)&b1;
        *(uint2*)(Tb + (size_t)q * HWc + pix0) = p0;
        *(uint2*)(Tb + (size_t)q * HWc + pix1) = p1;
    }

    // step0 on channel 3: k = dj*3+di multiplies x15[i+di-1, j+dj-1].
    float o00 = t00[9], o01 = t01[9], o10 = t10[9], o11 = t11[9];
    #pragma unroll
    for (int dj = 0; dj < 3; ++dj)
        #pragma unroll
        for (int di = 0; di < 3; ++di) {
            int k = dj * 3 + di;
            o00 += w[di][dj]         * t00[k];
            o01 += w[di][dj + 1]     * t01[k];
            o10 += w[di + 1][dj]     * t10[k];
            o11 += w[di + 1][dj + 1] * t11[k];
        }
    float* ob = out + (size_t)b * Td * HWc;
    float2 v0; v0.x = o00; v0.y = o01;
    float2 v1; v1.x = o10; v1.y = o11;
    *(float2*)(ob + pix0) = v0;
    *(float2*)(ob + pix1) = v1;
}

// ---------------------------------------------------------------------------
// Kernel 2a (preferred): lane-column fused kernel (r14 logic, verified
// correct; now launch_bounds(448,2) -> 128-VGPR cap, no spill; fma_mix taps).
// Wave g owns region rows rs..rs+10 (rs=1+11g), lane = region col. Column
// state xw[13] in registers; horizontal neighbors via DPP lane shifts;
// vertical in-register; only 2 group-boundary rows cross LDS per step.
// Ring rows/cols never updated; validity after 6 steps = exactly the core.
// Out-of-image pixels forced 0 every step.
// 640 blocks = 8 b * 8 row-tiles * 10 col-tiles.
// ---------------------------------------------------------------------------
__global__ __launch_bounds__(KTHR, 2)
void fused6_lane_kernel(const float* __restrict__ xin,   // out slot t-1 base
                        const __half2* __restrict__ T,
                        float* __restrict__ xout) {      // out slot t base
    __shared__ float bndF[2][KG][64];
    __shared__ float bndL[2][KG][64];

    int tile = blockIdx.x;              // 640
    int b   = tile / 80;
    int rem = tile - b * 80;
    int tr  = rem / 10;
    int tc  = rem - tr * 10;
    int ri  = tr * KCR - KH;
    int rj  = tc * KCC - KH;

    int tid  = threadIdx.x;
    int g    = tid >> 6;                // wave-uniform group 0..6
    int lane = tid & 63;

    int  gj     = rj + lane;
    bool colin  = (unsigned)gj < (unsigned)Wd;
    bool lanein = (lane >= 1) && (lane <= KTC - 2);
    int  gjc    = min(max(gj, 0), Wd - 1);

    int rs = 1 + g * KR;

    const float* xb = xin + (size_t)b * Td * HWc;
    const __half2* Tb = T + (size_t)b * 5 * HWc;

    // Initial column state: rows rs-1 .. rs+11, zero outside image.
    float xw[KR + 2];
    #pragma unroll
    for (int k = 0; k < KR + 2; ++k) {
        int row = rs - 1 + k;
        int gi  = ri + row;
        bool in = ((unsigned)gi < (unsigned)Hd) && colin && (row <= KTR - 1);
        int gic = min(max(gi, 0), Hd - 1);
        float v = xb[gic * Wd + gjc];
        xw[k] = in ? v : 0.0f;
    }

    // T coefs (as raw uints; clamped addresses feed only masked outputs).
    unsigned treg[KR][5];
    #pragma unroll
    for (int j = 0; j < KR; ++j) {
        int gi  = ri + rs + j;
        int gic = min(max(gi, 0), Hd - 1);
        const unsigned* tp = (const unsigned*)(Tb + gic * Wd + gjc);
        #pragma unroll
        for (int q = 0; q < 5; ++q)
            treg[j][q] = tp[(size_t)q * HWc];
    }

    int p = 0;
    #pragma unroll
    for (int s = 1; s <= 6; ++s) {
        float pC = xw[0], pL = lane_left(pC), pR = lane_right(pC);
        float cC = xw[1], cL = lane_left(cC), cR = lane_right(cC);
        #pragma unroll
        for (int j = 1; j <= KR; ++j) {
            float nC = xw[j + 1];
            float nL = lane_left(nC);
            float nR = lane_right(nC);
            unsigned h0 = treg[j - 1][0], h1 = treg[j - 1][1],
                     h2 = treg[j - 1][2], h3 = treg[j - 1][3],
                     h4 = treg[j - 1][4];
            // k = dj*3+di multiplies x[r+di-1][c+dj-1]
            float a = hi_half_f32(h4);          // T9
            FMAMIX_LO(a, pL, h0);               // k0: T0
            FMAMIX_HI(a, cL, h0);               // k1: T1
            FMAMIX_LO(a, nL, h1);               // k2: T2
            FMAMIX_HI(a, pC, h1);               // k3: T3
            FMAMIX_LO(a, cC, h2);               // k4: T4
            FMAMIX_HI(a, nC, h2);               // k5: T5
            FMAMIX_LO(a, pR, h3);               // k6: T6
            FMAMIX_HI(a, cR, h3);               // k7: T7
            FMAMIX_LO(a, nR, h4);               // k8: T8
            if ((s & 1) == 0) a = 1.0f / (1.0f + __expf(-a));

            int row = rs + j - 1;
            int gi  = ri + row;
            bool okpix = ((unsigned)gi < (unsigned)Hd) && colin;
            bool upd   = (row <= KTR - 2) && lanein;
            float val  = okpix ? a : 0.0f;
            xw[j] = upd ? val : xw[j];

            pL = cL; pC = cC; pR = cR;
            cL = nL; cC = nC; cR = nR;
        }
        bndF[p][g][lane] = xw[1];
        bndL[p][g][lane] = xw[KR];
        __syncthreads();
        if (g > 0)      xw[0]      = bndL[p][g - 1][lane];
        if (g < KG - 1) xw[KR + 1] = bndF[p][g + 1][lane];
        p ^= 1;
    }

    // Store the 64x52 core (region rows 6..69, cols 6..57), masked to image.
    float* ob = xout + (size_t)b * Td * HWc;
    bool storec = (lane >= KH) && (lane <= KTC - 1 - KH) && colin;
    #pragma unroll
    for (int j = 1; j <= KR; ++j) {
        int row = rs + j - 1;
        if (row >= KH && row <= KTR - 1 - KH) {     // wave-uniform
            int gi = ri + row;
            if (storec) ob[gi * Wd + gj] = xw[j];
        }
    }
}

// ---------------------------------------------------------------------------
// Kernel 2b (fallback, r15 proven + fma_mix): wide LDS ping-pong kernel.
// ---------------------------------------------------------------------------
__global__ __launch_bounds__(WTHR, 2)
void fused6_wide_kernel(const float* __restrict__ xin,
                        const __half2* __restrict__ T,
                        float* __restrict__ xout) {
    __shared__ float sA[WTR * WLP];
    __shared__ float sB[WTR * WLP];

    int tile = blockIdx.x;          // 256
    int b  = tile >> 5;
    int tr = (tile >> 3) & 3;
    int tc = tile & 7;
    int ri = tr * WCR - WH;
    int rj = tc * WCC - WH;

    const float* xb = xin + (size_t)b * Td * HWc;
    const __half2* Tb = T + (size_t)b * 5 * HWc;
    int tid = threadIdx.x;

    for (int idx = tid; idx < WTR * WTC; idx += WTHR) {
        int r = idx / WTC, c = idx - r * WTC;
        int gi = ri + r, gj = rj + c;
        float v = 0.0f;
        if ((unsigned)gi < (unsigned)Hd && (unsigned)gj < (unsigned)Wd)
            v = xb[gi * Wd + gj];
        sA[r * WLP + c] = v;
    }
    for (int idx = tid; idx < 2 * WTC; idx += WTHR) {
        int r = (idx < WTC) ? 0 : (WTR - 1);
        int c = (idx < WTC) ? idx : idx - WTC;
        sB[r * WLP + c] = 0.0f;
    }
    for (int idx = tid; idx < 2 * WTR; idx += WTHR) {
        int r = (idx < WTR) ? idx : idx - WTR;
        int c = (idx < WTR) ? 0 : (WTC - 1);
        sB[r * WLP + c] = 0.0f;
    }

    int g  = tid / WTC;
    int c  = tid - g * WTC;
    int rs = 1 + g * WRPG;
    bool colint = (c >= 1) && (c <= WTC - 2);
    bool active = (g < WNG) && colint;
    int  gj     = rj + c;
    bool colin  = (unsigned)gj < (unsigned)Wd;

    unsigned treg[WRPG][5];
    #pragma unroll
    for (int jj = 0; jj < WRPG; ++jj) {
        int r  = rs + jj;
        int gi = ri + r;
        bool ok = active && (r <= WTR - 2) && ((unsigned)gi < (unsigned)Hd) && colin;
        #pragma unroll
        for (int q = 0; q < 5; ++q) {
            unsigned v = 0u;
            if (ok) v = *(const unsigned*)(Tb + (size_t)q * HWc + gi * Wd + gj);
            treg[jj][q] = v;
        }
    }
    __syncthreads();

    float* cur = sA;
    float* nxt = sB;

    #pragma unroll
    for (int s = 1; s <= 6; ++s) {
        if (active) {
            float w00 = cur[(rs - 1) * WLP + c - 1];
            float w01 = cur[(rs - 1) * WLP + c];
            float w02 = cur[(rs - 1) * WLP + c + 1];
            float w10 = cur[rs * WLP + c - 1];
            float w11 = cur[rs * WLP + c];
            float w12 = cur[rs * WLP + c + 1];
            #pragma unroll
            for (int jj = 0; jj < WRPG; ++jj) {
                int r  = rs + jj;
                int r2 = (r + 1 <= WTR - 1) ? (r + 1) : (WTR - 1);
                float w20 = cur[r2 * WLP + c - 1];
                float w21 = cur[r2 * WLP + c];
                float w22 = cur[r2 * WLP + c + 1];

                unsigned h0 = treg[jj][0], h1 = treg[jj][1], h2 = treg[jj][2],
                         h3 = treg[jj][3], h4 = treg[jj][4];
                // k = dj*3+di multiplies x[r+di-1][c+dj-1]
                float a = hi_half_f32(h4);      // T9
                FMAMIX_LO(a, w00, h0);
                FMAMIX_HI(a, w10, h0);
                FMAMIX_LO(a, w20, h1);
                FMAMIX_HI(a, w01, h1);
                FMAMIX_LO(a, w11, h2);
                FMAMIX_HI(a, w21, h2);
                FMAMIX_LO(a, w02, h3);
                FMAMIX_HI(a, w12, h3);
                FMAMIX_LO(a, w22, h4);
                if ((s & 1) == 0) a = 1.0f / (1.0f + __expf(-a));

                int gi = ri + r;
                bool rowok = (r <= WTR - 2);
                bool inimg = ((unsigned)gi < (unsigned)Hd) && colin;
                if (rowok) nxt[r * WLP + c] = inimg ? a : 0.0f;

                w00 = w10; w01 = w11; w02 = w12;
                w10 = w20; w11 = w21; w12 = w22;
            }
        }
        __syncthreads();
        float* tmp = cur; cur = nxt; nxt = tmp;
    }

    float* ob = xout + (size_t)b * Td * HWc;
    for (int idx = tid; idx < WCR * WCC; idx += WTHR) {
        int rr = idx >> 6, cc = idx & 63;
        ob[(ri + WH + rr) * Wd + (rj + WH + cc)] = cur[(WH + rr) * WLP + (WH + cc)];
    }
}

// ---------------------------------------------------------------------------
// Workspace: T only (B*5*H*W half2 = 40 MB).
// ---------------------------------------------------------------------------
extern "C" void kernel_launch(void* const* d_in, const int* in_sizes, int n_in,
                              void* d_out, int out_size, void* d_ws, size_t ws_size,
                              hipStream_t stream) {
    const float* x  = (const float*)d_in[0];
    const float* Wu = (const float*)d_in[1];
    const float* bu = (const float*)d_in[2];
    float* out = (float*)d_out;
    __half2* T = (__half2*)d_ws;

    conv_step0_kernel<<<1024, VTHR, 0, stream>>>(x, Wu, bu, T, out);

    // Deterministic spill gate: use the lane kernel only if it compiled
    // without scratch (localSizeBytes == 0). Host-side query, capture-safe.
    hipFuncAttributes attr;
    hipError_t qe = hipFuncGetAttributes(&attr, (const void*)fused6_lane_kernel);
    bool useLane = (qe == hipSuccess) && (attr.localSizeBytes == 0);

    if (useLane) {
        for (int t = 1; t < Td; ++t)
            fused6_lane_kernel<<<640, KTHR, 0, stream>>>(
                out + (size_t)(t - 1) * HWc, T, out + (size_t)t * HWc);
    } else {
        for (int t = 1; t < Td; ++t)
            fused6_wide_kernel<<<256, WTHR, 0, stream>>>(
                out + (size_t)(t - 1) * HWc, T, out + (size_t)t * HWc);
    }
}

// Round 17
// 514.635 us; speedup vs baseline: 2.3285x; 1.0355x over previous
//
#include <hip/hip_runtime.h>
#include <hip/hip_fp16.h>
#include <math.h>

// Problem constants: B=8, Tt=16, C=1, H=W=512, 4 in-channels, 10 T-planes.
#define Bd 8
#define Td 16
#define Hd 512
#define Wd 512
#define HWc (Hd * Wd)          // 262144
#define NPIX (Bd * HWc)        // 2,097,152

// ---------------- conv tiling: 16x16 tile, 1 px/thread, 256 threads ----------
#define CT  16                 // tile edge
#define CR  18                 // region edge
#define CP  20                 // LDS row pitch (words)
#define CTH2 256

// ---------------- wide fused kernel (fallback): 128x64 core, halo 6 ----------
#define WCR 128
#define WCC 64
#define WH  6
#define WTR 140
#define WTC 76
#define WLP 77
#define WTHR 1024
#define WRPG 11
#define WNG 13

// ---------------- lane-column fused kernel -----------------------------------
#define KCR 64                 // core rows
#define KCC 52                 // core cols
#define KH  6                  // halo
#define KTR 76                 // region rows
#define KTC 64                 // region cols == lanes of one wave
#define KG  7                  // waves (row groups) per block
#define KR  11                 // owned rows per thread
#define KTHR (KG * 64)         // 448 threads

// v_fma_mix_f32: acc(f32) += w(f32) * h.lo/h.hi(f16) in ONE instruction.
#define FMAMIX_LO(acc, wv, hv) \
    asm("v_fma_mix_f32 %0, %1, %2, %0 op_sel:[0,0,0] op_sel_hi:[0,1,0]" \
        : "+v"(acc) : "v"(wv), "v"(hv))
#define FMAMIX_HI(acc, wv, hv) \
    asm("v_fma_mix_f32 %0, %1, %2, %0 op_sel:[0,1,0] op_sel_hi:[0,1,0]" \
        : "+v"(acc) : "v"(wv), "v"(hv))

__device__ __forceinline__ float hi_half_f32(unsigned h) {
    __half2 hh = *(__half2*)&h;
    return __half2float(__high2half(hh));
}

// Whole-wave lane shifts (verified r14): left = lane-1, right = lane+1.
__device__ __forceinline__ float lane_left(float v) {
#if __has_builtin(__builtin_amdgcn_mov_dpp)
    return __int_as_float(__builtin_amdgcn_mov_dpp(__float_as_int(v),
                                                   0x138, 0xf, 0xf, true));
#else
    return __shfl_up(v, 1);
#endif
}
__device__ __forceinline__ float lane_right(float v) {
#if __has_builtin(__builtin_amdgcn_mov_dpp)
    return __int_as_float(__builtin_amdgcn_mov_dpp(__float_as_int(v),
                                                   0x130, 0xf, 0xf, true));
#else
    return __shfl_down(v, 1);
#endif
}

// ---------------------------------------------------------------------------
// Kernel 1 (NEW o-outer form): T = conv2d(x[:,-4:,0],W)+b fused with
// xt0 = stencil(x[:,15,0], T_fp32) -> out[:,0].
// 1 px/thread; the 36-tap x-window lives in 36 VGPRs; for each output
// channel o the 36 weights Wu[o*36 .. o*36+35] are CONTIGUOUS -> batched
// scalar loads; inner loop = pure v_fmac(v, s, v). Accumulator live range
// is 1 reg -> ~55 VGPR total, no spill, 32-wave occupancy.
// T stored as half2 pairs: plane q holds (T[2q], T[2q+1]); layout (B,5,H,W).
// ---------------------------------------------------------------------------
__global__ __launch_bounds__(CTH2)
void conv_step0_kernel(const float* __restrict__ x,
                       const float* __restrict__ Wu,
                       const float* __restrict__ bu,
                       __half2* __restrict__ T,
                       float* __restrict__ out) {
    __shared__ float sX[4][CR][CP];     // 5.76 KB

    int bx  = blockIdx.x;               // 8192 = 8 b * 32 * 32 tiles
    int b   = bx >> 10;
    int rem = bx & 1023;
    int by  = rem >> 5;                 // tile row band 0..31
    int bc  = rem & 31;                 // tile col band 0..31
    int i0  = by * CT;
    int j0  = bc * CT;

    const float* xb = x + ((size_t)b * Td + 12) * HWc;   // channel c -> slice 12+c
    int tid = threadIdx.x;

    // Stage the 4-channel 18x18 region (zeros outside image).
    for (int idx = tid; idx < 4 * CR * CR; idx += CTH2) {
        int ch = idx / (CR * CR);
        int r2 = idx - ch * (CR * CR);
        int r  = r2 / CR;
        int c  = r2 - r * CR;
        int gi = i0 + r - 1, gj = j0 + c - 1;
        float v = 0.0f;
        if ((unsigned)gi < (unsigned)Hd && (unsigned)gj < (unsigned)Wd)
            v = xb[(size_t)ch * HWc + gi * Wd + gj];
        sX[ch][r][c] = v;
    }
    __syncthreads();

    int tx = tid & 15;                  // tile col
    int ty = tid >> 4;                  // tile row

    // Window in z order matching Wu layout: z = (ch*3 + kh)*3 + kw.
    float xf[36];
    #pragma unroll
    for (int ch = 0; ch < 4; ++ch)
        #pragma unroll
        for (int kh = 0; kh < 3; ++kh)
            #pragma unroll
            for (int kw = 0; kw < 3; ++kw)
                xf[(ch * 3 + kh) * 3 + kw] = sX[ch][ty + kh][tx + kw];

    int gi = i0 + ty;
    int gj = j0 + tx;
    size_t pix = (size_t)gi * Wd + gj;
    __half2* Tb = T + (size_t)b * 5 * HWc;

    float o0 = 0.0f;                    // step0 accumulator
    float accPrev = 0.0f;
    #pragma unroll
    for (int o = 0; o < 10; ++o) {
        const float* wo = Wu + o * 36;  // 36 contiguous weights -> s_load_dwordx
        float acc = bu[o];
        #pragma unroll
        for (int z = 0; z < 36; ++z)
            acc += xf[z] * wo[z];

        // step0 inline: k = dj*3+di multiplies x15[i+di-1, j+dj-1];
        // for o = k < 9: di = o%3, dj = o/3; channel 3 window = xf[27 + ...].
        if (o < 9)
            o0 += xf[(3 * 3 + (o % 3)) * 3 + (o / 3)] * acc;
        else
            o0 += acc;                  // T9 additive term

        if (o & 1) {
            __half2 h = __floats2half2_rn(accPrev, acc);
            *(unsigned*)(Tb + (size_t)(o >> 1) * HWc + pix) = *(unsigned*)&h;
        }
        accPrev = acc;
    }

    out[(size_t)b * Td * HWc + pix] = o0;
}

// ---------------------------------------------------------------------------
// Kernel 2a (preferred, r16 verbatim): lane-column fused kernel.
// ---------------------------------------------------------------------------
__global__ __launch_bounds__(KTHR, 2)
void fused6_lane_kernel(const float* __restrict__ xin,   // out slot t-1 base
                        const __half2* __restrict__ T,
                        float* __restrict__ xout) {      // out slot t base
    __shared__ float bndF[2][KG][64];
    __shared__ float bndL[2][KG][64];

    int tile = blockIdx.x;              // 640
    int b   = tile / 80;
    int rem = tile - b * 80;
    int tr  = rem / 10;
    int tc  = rem - tr * 10;
    int ri  = tr * KCR - KH;
    int rj  = tc * KCC - KH;

    int tid  = threadIdx.x;
    int g    = tid >> 6;                // wave-uniform group 0..6
    int lane = tid & 63;

    int  gj     = rj + lane;
    bool colin  = (unsigned)gj < (unsigned)Wd;
    bool lanein = (lane >= 1) && (lane <= KTC - 2);
    int  gjc    = min(max(gj, 0), Wd - 1);

    int rs = 1 + g * KR;

    const float* xb = xin + (size_t)b * Td * HWc;
    const __half2* Tb = T + (size_t)b * 5 * HWc;

    float xw[KR + 2];
    #pragma unroll
    for (int k = 0; k < KR + 2; ++k) {
        int row = rs - 1 + k;
        int gi  = ri + row;
        bool in = ((unsigned)gi < (unsigned)Hd) && colin && (row <= KTR - 1);
        int gic = min(max(gi, 0), Hd - 1);
        float v = xb[gic * Wd + gjc];
        xw[k] = in ? v : 0.0f;
    }

    unsigned treg[KR][5];
    #pragma unroll
    for (int j = 0; j < KR; ++j) {
        int gi  = ri + rs + j;
        int gic = min(max(gi, 0), Hd - 1);
        const unsigned* tp = (const unsigned*)(Tb + gic * Wd + gjc);
        #pragma unroll
        for (int q = 0; q < 5; ++q)
            treg[j][q] = tp[(size_t)q * HWc];
    }

    int p = 0;
    #pragma unroll
    for (int s = 1; s <= 6; ++s) {
        float pC = xw[0], pL = lane_left(pC), pR = lane_right(pC);
        float cC = xw[1], cL = lane_left(cC), cR = lane_right(cC);
        #pragma unroll
        for (int j = 1; j <= KR; ++j) {
            float nC = xw[j + 1];
            float nL = lane_left(nC);
            float nR = lane_right(nC);
            unsigned h0 = treg[j - 1][0], h1 = treg[j - 1][1],
                     h2 = treg[j - 1][2], h3 = treg[j - 1][3],
                     h4 = treg[j - 1][4];
            // k = dj*3+di multiplies x[r+di-1][c+dj-1]
            float a = hi_half_f32(h4);          // T9
            FMAMIX_LO(a, pL, h0);               // k0: T0
            FMAMIX_HI(a, cL, h0);               // k1: T1
            FMAMIX_LO(a, nL, h1);               // k2: T2
            FMAMIX_HI(a, pC, h1);               // k3: T3
            FMAMIX_LO(a, cC, h2);               // k4: T4
            FMAMIX_HI(a, nC, h2);               // k5: T5
            FMAMIX_LO(a, pR, h3);               // k6: T6
            FMAMIX_HI(a, cR, h3);               // k7: T7
            FMAMIX_LO(a, nR, h4);               // k8: T8
            if ((s & 1) == 0) a = 1.0f / (1.0f + __expf(-a));

            int row = rs + j - 1;
            int gi  = ri + row;
            bool okpix = ((unsigned)gi < (unsigned)Hd) && colin;
            bool upd   = (row <= KTR - 2) && lanein;
            float val  = okpix ? a : 0.0f;
            xw[j] = upd ? val : xw[j];

            pL = cL; pC = cC; pR = cR;
            cL = nL; cC = nC; cR = nR;
        }
        bndF[p][g][lane] = xw[1];
        bndL[p][g][lane] = xw[KR];
        __syncthreads();
        if (g > 0)      xw[0]      = bndL[p][g - 1][lane];
        if (g < KG - 1) xw[KR + 1] = bndF[p][g + 1][lane];
        p ^= 1;
    }

    float* ob = xout + (size_t)b * Td * HWc;
    bool storec = (lane >= KH) && (lane <= KTC - 1 - KH) && colin;
    #pragma unroll
    for (int j = 1; j <= KR; ++j) {
        int row = rs + j - 1;
        if (row >= KH && row <= KTR - 1 - KH) {     // wave-uniform
            int gi = ri + row;
            if (storec) ob[gi * Wd + gj] = xw[j];
        }
    }
}

// ---------------------------------------------------------------------------
// Kernel 2b (fallback, r16 verbatim): wide LDS ping-pong kernel + fma_mix.
// ---------------------------------------------------------------------------
__global__ __launch_bounds__(WTHR, 2)
void fused6_wide_kernel(const float* __restrict__ xin,
                        const __half2* __restrict__ T,
                        float* __restrict__ xout) {
    __shared__ float sA[WTR * WLP];
    __shared__ float sB[WTR * WLP];

    int tile = blockIdx.x;          // 256
    int b  = tile >> 5;
    int tr = (tile >> 3) & 3;
    int tc = tile & 7;
    int ri = tr * WCR - WH;
    int rj = tc * WCC - WH;

    const float* xb = xin + (size_t)b * Td * HWc;
    const __half2* Tb = T + (size_t)b * 5 * HWc;
    int tid = threadIdx.x;

    for (int idx = tid; idx < WTR * WTC; idx += WTHR) {
        int r = idx / WTC, c = idx - r * WTC;
        int gi = ri + r, gj = rj + c;
        float v = 0.0f;
        if ((unsigned)gi < (unsigned)Hd && (unsigned)gj < (unsigned)Wd)
            v = xb[gi * Wd + gj];
        sA[r * WLP + c] = v;
    }
    for (int idx = tid; idx < 2 * WTC; idx += WTHR) {
        int r = (idx < WTC) ? 0 : (WTR - 1);
        int c = (idx < WTC) ? idx : idx - WTC;
        sB[r * WLP + c] = 0.0f;
    }
    for (int idx = tid; idx < 2 * WTR; idx += WTHR) {
        int r = (idx < WTR) ? idx : idx - WTR;
        int c = (idx < WTR) ? 0 : (WTC - 1);
        sB[r * WLP + c] = 0.0f;
    }

    int g  = tid / WTC;
    int c  = tid - g * WTC;
    int rs = 1 + g * WRPG;
    bool colint = (c >= 1) && (c <= WTC - 2);
    bool active = (g < WNG) && colint;
    int  gj     = rj + c;
    bool colin  = (unsigned)gj < (unsigned)Wd;

    unsigned treg[WRPG][5];
    #pragma unroll
    for (int jj = 0; jj < WRPG; ++jj) {
        int r  = rs + jj;
        int gi = ri + r;
        bool ok = active && (r <= WTR - 2) && ((unsigned)gi < (unsigned)Hd) && colin;
        #pragma unroll
        for (int q = 0; q < 5; ++q) {
            unsigned v = 0u;
            if (ok) v = *(const unsigned*)(Tb + (size_t)q * HWc + gi * Wd + gj);
            treg[jj][q] = v;
        }
    }
    __syncthreads();

    float* cur = sA;
    float* nxt = sB;

    #pragma unroll
    for (int s = 1; s <= 6; ++s) {
        if (active) {
            float w00 = cur[(rs - 1) * WLP + c - 1];
            float w01 = cur[(rs - 1) * WLP + c];
            float w02 = cur[(rs - 1) * WLP + c + 1];
            float w10 = cur[rs * WLP + c - 1];
            float w11 = cur[rs * WLP + c];
            float w12 = cur[rs * WLP + c + 1];
            #pragma unroll
            for (int jj = 0; jj < WRPG; ++jj) {
                int r  = rs + jj;
                int r2 = (r + 1 <= WTR - 1) ? (r + 1) : (WTR - 1);
                float w20 = cur[r2 * WLP + c - 1];
                float w21 = cur[r2 * WLP + c];
                float w22 = cur[r2 * WLP + c + 1];

                unsigned h0 = treg[jj][0], h1 = treg[jj][1], h2 = treg[jj][2],
                         h3 = treg[jj][3], h4 = treg[jj][4];
                float a = hi_half_f32(h4);      // T9
                FMAMIX_LO(a, w00, h0);
                FMAMIX_HI(a, w10, h0);
                FMAMIX_LO(a, w20, h1);
                FMAMIX_HI(a, w01, h1);
                FMAMIX_LO(a, w11, h2);
                FMAMIX_HI(a, w21, h2);
                FMAMIX_LO(a, w02, h3);
                FMAMIX_HI(a, w12, h3);
                FMAMIX_LO(a, w22, h4);
                if ((s & 1) == 0) a = 1.0f / (1.0f + __expf(-a));

                int gi = ri + r;
                bool rowok = (r <= WTR - 2);
                bool inimg = ((unsigned)gi < (unsigned)Hd) && colin;
                if (rowok) nxt[r * WLP + c] = inimg ? a : 0.0f;

                w00 = w10; w01 = w11; w02 = w12;
                w10 = w20; w11 = w21; w12 = w22;
            }
        }
        __syncthreads();
        float* tmp = cur; cur = nxt; nxt = tmp;
    }

    float* ob = xout + (size_t)b * Td * HWc;
    for (int idx = tid; idx < WCR * WCC; idx += WTHR) {
        int rr = idx >> 6, cc = idx & 63;
        ob[(ri + WH + rr) * Wd + (rj + WH + cc)] = cur[(WH + rr) * WLP + (WH + cc)];
    }
}

// ---------------------------------------------------------------------------
// Workspace: T only (B*5*H*W half2 = 40 MB).
// ---------------------------------------------------------------------------
extern "C" void kernel_launch(void* const* d_in, const int* in_sizes, int n_in,
                              void* d_out, int out_size, void* d_ws, size_t ws_size,
                              hipStream_t stream) {
    const float* x  = (const float*)d_in[0];
    const float* Wu = (const float*)d_in[1];
    const float* bu = (const float*)d_in[2];
    float* out = (float*)d_out;
    __half2* T = (__half2*)d_ws;

    conv_step0_kernel<<<8192, CTH2, 0, stream>>>(x, Wu, bu, T, out);

    // Deterministic spill gate: use the lane kernel only if it compiled
    // without scratch (localSizeBytes == 0). Host-side query, capture-safe.
    hipFuncAttributes attr;
    hipError_t qe = hipFuncGetAttributes(&attr, (const void*)fused6_lane_kernel);
    bool useLane = (qe == hipSuccess) && (attr.localSizeBytes == 0);

    if (useLane) {
        for (int t = 1; t < Td; ++t)
            fused6_lane_kernel<<<640, KTHR, 0, stream>>>(
                out + (size_t)(t - 1) * HWc, T, out + (size_t)t * HWc);
    } else {
        for (int t = 1; t < Td; ++t)
            fused6_wide_kernel<<<256, WTHR, 0, stream>>>(
                out + (size_t)(t - 1) * HWc, T, out + (size_t)t * HWc);
    }
}